// Round 1
// baseline (418.938 us; speedup 1.0000x reference)
//
#include <hip/hip_runtime.h>
#include <math.h>

// Problem constants (SimpleSSM): u(B,DI,L), A(S), B_mat(S,DI), C_mat(DO,S), D_mat(DO,DI), h0(S)
#define BZ 8
#define DI 256
#define DS 512
#define DOUT 256
#define LL 4096
#define BS (BZ * DS)   // 4096 (b,s) states
#define CH 64          // number of time chunks
#define CT 64          // timesteps per chunk; CH*CT == LL

// ---------------------------------------------------------------------------
// k_prep: A_diag = -softplus(A_unconstrained); power table apow[j][s] = a^j, j=0..CT
// ---------------------------------------------------------------------------
__global__ __launch_bounds__(256) void k_prep(const float* __restrict__ Au,
                                              float* __restrict__ apow) {
    int s = blockIdx.x * 256 + threadIdx.x;
    if (s >= DS) return;
    float x = Au[s];
    float sp = (x > 15.f) ? x : log1pf(expf(x));
    float ad = -sp;                       // A_diag[s]
    float p = 1.f;
    apow[s] = 1.f;
    for (int j = 1; j <= CT; ++j) { p *= ad; apow[j * DS + s] = p; }
}

// ---------------------------------------------------------------------------
// k_bu: Bu[l][b][s] = sum_i u[b][i][l] * Bm[s][i]   (64x64 tile per block)
// ---------------------------------------------------------------------------
__global__ __launch_bounds__(256) void k_bu(const float* __restrict__ u,
                                            const float* __restrict__ Bm,
                                            float* __restrict__ Bu) {
    __shared__ float Ut[16][68];   // [k][l]   stride 68: 16B aligned, no bad conflicts
    __shared__ float Bt[16][68];   // [k][s]
    const int tid = threadIdx.x;
    const int l0 = blockIdx.x * 64;
    const int s0 = blockIdx.y * 64;
    const int b  = blockIdx.z;
    const int tl = tid & 15, ts = tid >> 4;   // micro-tile: l = 4*tl+x, s = 4*ts+y
    const int ui = tid >> 6, ul = tid & 63;   // u staging: (k-row, l)
    const int bi = tid & 15, bsr = tid >> 4;  // B staging: (k, s-row)

    float acc[4][4];
#pragma unroll
    for (int x = 0; x < 4; ++x)
#pragma unroll
        for (int y = 0; y < 4; ++y) acc[x][y] = 0.f;

    for (int kk = 0; kk < DI; kk += 16) {
        const float* up = u + ((size_t)b * DI + kk + ui) * LL + l0 + ul;
#pragma unroll
        for (int r = 0; r < 4; ++r)
            Ut[ui + 4 * r][ul] = up[(size_t)(4 * r) * LL];
#pragma unroll
        for (int r = 0; r < 4; ++r)
            Bt[bi][bsr + 16 * r] = Bm[(size_t)(s0 + bsr + 16 * r) * DI + kk + bi];
        __syncthreads();
#pragma unroll
        for (int k = 0; k < 16; ++k) {
            const float4 a4 = *(const float4*)&Ut[k][4 * tl];
            const float4 b4 = *(const float4*)&Bt[k][4 * ts];
            const float av[4] = {a4.x, a4.y, a4.z, a4.w};
            const float bv[4] = {b4.x, b4.y, b4.z, b4.w};
#pragma unroll
            for (int x = 0; x < 4; ++x)
#pragma unroll
                for (int y = 0; y < 4; ++y) acc[x][y] += av[x] * bv[y];
        }
        __syncthreads();
    }
#pragma unroll
    for (int x = 0; x < 4; ++x) {
        float4 o = make_float4(acc[x][0], acc[x][1], acc[x][2], acc[x][3]);
        *(float4*)&Bu[(size_t)(l0 + 4 * tl + x) * BS + (size_t)b * DS + s0 + 4 * ts] = o;
    }
}

// ---------------------------------------------------------------------------
// k_scan_local: per-chunk zero-init scan, in-place on Bu; write chunk finals
// ---------------------------------------------------------------------------
__global__ __launch_bounds__(256) void k_scan_local(float* __restrict__ Bu,
                                                    float* __restrict__ finals,
                                                    const float* __restrict__ apow) {
    const int c = blockIdx.x;
    const int bs = blockIdx.y * 256 + threadIdx.x;
    const int s = bs & (DS - 1);
    const float a = apow[DS + s];         // a^1
    float acc = 0.f;
    size_t base = (size_t)c * CT * BS + bs;
    for (int j = 0; j < CT; ++j) {
        float v = Bu[base + (size_t)j * BS];
        acc = acc * a + v;
        Bu[base + (size_t)j * BS] = acc;
    }
    finals[c * BS + bs] = acc;
}

// ---------------------------------------------------------------------------
// k_carry: sequential scan over the 64 chunk carries (parallel over b,s)
// carry entering chunk c: carry[0]=h0; carry[c] = a^CT * carry[c-1] + final[c-1]
// ---------------------------------------------------------------------------
__global__ __launch_bounds__(256) void k_carry(const float* __restrict__ finals,
                                               float* __restrict__ carries,
                                               const float* __restrict__ apow,
                                               const float* __restrict__ h0) {
    const int bs = blockIdx.x * 256 + threadIdx.x;
    const int s = bs & (DS - 1);
    const float aT = apow[CT * DS + s];
    float carry = h0[s];
    for (int c = 0; c < CH; ++c) {
        carries[c * BS + bs] = carry;
        carry = aT * carry + finals[c * BS + bs];
    }
}

// ---------------------------------------------------------------------------
// k_correct: xs[t][bs] = local[t][bs] + a^{(t%CT)+1} * carry[t/CT][bs]  (in place)
// ---------------------------------------------------------------------------
__global__ __launch_bounds__(256) void k_correct(float* __restrict__ Bu,
                                                 const float* __restrict__ carries,
                                                 const float* __restrict__ apow) {
    const size_t idx = (size_t)blockIdx.x * 256 + threadIdx.x;  // over LL*BS
    const int t = (int)(idx >> 12);        // /BS (4096)
    const int bs = (int)(idx & (BS - 1));
    const int c = t >> 6, j = t & (CT - 1);
    const int s = bs & (DS - 1);
    Bu[idx] += apow[(j + 1) * DS + s] * carries[c * BS + bs];
}

// ---------------------------------------------------------------------------
// k_out: Y[b][o][l] = sum_s Cm[o][s]*X[l][b][s] + sum_i Dm[o][i]*u[b][i][l]
// 64(l) x 64(o) tile per block
// ---------------------------------------------------------------------------
__global__ __launch_bounds__(256) void k_out(const float* __restrict__ Cm,
                                             const float* __restrict__ Dm,
                                             const float* __restrict__ X,
                                             const float* __restrict__ u,
                                             float* __restrict__ Y) {
    __shared__ float At[16][68];    // [k][o]
    __shared__ float Bt2[16][68];   // [k][l]
    const int tid = threadIdx.x;
    const int l0 = blockIdx.x * 64;
    const int o0 = blockIdx.y * 64;
    const int b  = blockIdx.z;
    const int tl = tid & 15, to = tid >> 4;   // l = 4*tl+x, o = 4*to+y
    const int ck = tid & 15, cor = tid >> 4;  // staging: (k, row)
    const int uk = tid >> 6, ul = tid & 63;   // u staging: (k-row, l)

    float acc[4][4];
#pragma unroll
    for (int x = 0; x < 4; ++x)
#pragma unroll
        for (int y = 0; y < 4; ++y) acc[x][y] = 0.f;

    // phase 1: C (DOUT x DS) @ X_b (DS x LL)
    for (int kk = 0; kk < DS; kk += 16) {
#pragma unroll
        for (int r = 0; r < 4; ++r)
            At[ck][cor + 16 * r] = Cm[(size_t)(o0 + cor + 16 * r) * DS + kk + ck];
#pragma unroll
        for (int r = 0; r < 4; ++r)
            Bt2[ck][cor + 16 * r] = X[(size_t)(l0 + cor + 16 * r) * BS + (size_t)b * DS + kk + ck];
        __syncthreads();
#pragma unroll
        for (int k = 0; k < 16; ++k) {
            const float4 a4 = *(const float4*)&At[k][4 * to];
            const float4 b4 = *(const float4*)&Bt2[k][4 * tl];
            const float ov[4] = {a4.x, a4.y, a4.z, a4.w};
            const float lv[4] = {b4.x, b4.y, b4.z, b4.w};
#pragma unroll
            for (int x = 0; x < 4; ++x)
#pragma unroll
                for (int y = 0; y < 4; ++y) acc[x][y] += lv[x] * ov[y];
        }
        __syncthreads();
    }

    // phase 2: D (DOUT x DI) @ u_b (DI x LL)
    for (int kk = 0; kk < DI; kk += 16) {
#pragma unroll
        for (int r = 0; r < 4; ++r)
            At[ck][cor + 16 * r] = Dm[(size_t)(o0 + cor + 16 * r) * DI + kk + ck];
        const float* up = u + ((size_t)b * DI + kk + uk) * LL + l0 + ul;
#pragma unroll
        for (int r = 0; r < 4; ++r)
            Bt2[uk + 4 * r][ul] = up[(size_t)(4 * r) * LL];
        __syncthreads();
#pragma unroll
        for (int k = 0; k < 16; ++k) {
            const float4 a4 = *(const float4*)&At[k][4 * to];
            const float4 b4 = *(const float4*)&Bt2[k][4 * tl];
            const float ov[4] = {a4.x, a4.y, a4.z, a4.w};
            const float lv[4] = {b4.x, b4.y, b4.z, b4.w};
#pragma unroll
            for (int x = 0; x < 4; ++x)
#pragma unroll
                for (int y = 0; y < 4; ++y) acc[x][y] += lv[x] * ov[y];
        }
        __syncthreads();
    }

#pragma unroll
    for (int y = 0; y < 4; ++y) {
        float4 o = make_float4(acc[0][y], acc[1][y], acc[2][y], acc[3][y]);
        *(float4*)&Y[(size_t)b * DOUT * LL + (size_t)(o0 + 4 * to + y) * LL + l0 + 4 * tl] = o;
    }
}

// ---------------------------------------------------------------------------
extern "C" void kernel_launch(void* const* d_in, const int* in_sizes, int n_in,
                              void* d_out, int out_size, void* d_ws, size_t ws_size,
                              hipStream_t stream) {
    const float* u  = (const float*)d_in[0];
    const float* Au = (const float*)d_in[1];
    const float* Bm = (const float*)d_in[2];
    const float* Cm = (const float*)d_in[3];
    const float* Dm = (const float*)d_in[4];
    const float* h0 = (const float*)d_in[5];
    float* Y = (float*)d_out;

    // workspace layout (floats)
    float* ws      = (float*)d_ws;
    float* Bu      = ws;                                   // LL*BS   = 16,777,216  (67 MB)
    float* finals  = Bu + (size_t)LL * BS;                 // CH*BS   = 262,144
    float* carries = finals + (size_t)CH * BS;             // CH*BS   = 262,144
    float* apow    = carries + (size_t)CH * BS;            // (CT+1)*DS = 33,280

    k_prep<<<dim3((DS + 255) / 256), 256, 0, stream>>>(Au, apow);
    k_bu<<<dim3(LL / 64, DS / 64, BZ), 256, 0, stream>>>(u, Bm, Bu);
    k_scan_local<<<dim3(CH, BS / 256), 256, 0, stream>>>(Bu, finals, apow);
    k_carry<<<dim3(BS / 256), 256, 0, stream>>>(finals, carries, apow, h0);
    k_correct<<<dim3((int)(((size_t)LL * BS) / 256)), 256, 0, stream>>>(Bu, carries, apow);
    k_out<<<dim3(LL / 64, DOUT / 64, BZ), 256, 0, stream>>>(Cm, Dm, Bu, u, Y);
}

// Round 2
// 168.653 us; speedup vs baseline: 2.4840x; 2.4840x over previous
//
#include <hip/hip_runtime.h>
#include <math.h>

// SimpleSSM: u(B,DI,L) f32, A(S), B_mat(S,DI), C_mat(DO,S), D_mat(DO,DI), h0(S)
#define BZ 8
#define DI 256
#define DS 512
#define DOUT 256
#define LL 4096
#define BS (BZ * DS)   // 4096
#define CH 64
#define CT 64

typedef __bf16 bf16x8 __attribute__((ext_vector_type(8)));
typedef float f32x4 __attribute__((ext_vector_type(4)));

__device__ __forceinline__ ushort f2b(float f) {
    union { float f; unsigned u; } v; v.f = f;
    unsigned r = v.u + 0x7FFFu + ((v.u >> 16) & 1u);
    return (ushort)(r >> 16);
}
__device__ __forceinline__ float b2f(ushort h) {
    union { unsigned u; float f; } v; v.u = ((unsigned)h) << 16;
    return v.f;
}

// async 16B global->LDS (dst = wave-uniform base + lane*16)
__device__ __forceinline__ void gload16(const ushort* g, ushort* l) {
    __builtin_amdgcn_global_load_lds(
        (const __attribute__((address_space(1))) unsigned int*)g,
        (__attribute__((address_space(3))) unsigned int*)l,
        16, 0, 0);
}

// ---------------------------------------------------------------------------
// k_prep: apow[j][s]=a^j (a=-softplus), plus bf16 conversion of Bm/Cm/Dm
// ---------------------------------------------------------------------------
__global__ __launch_bounds__(256) void k_prep(const float* __restrict__ Au,
                                              float* __restrict__ apow,
                                              const float* __restrict__ Bm,
                                              const float* __restrict__ Cm,
                                              const float* __restrict__ Dm,
                                              ushort* __restrict__ Bmb,
                                              ushort* __restrict__ Cmb,
                                              ushort* __restrict__ Dmb) {
    const int t = blockIdx.x * 256 + threadIdx.x;
    const int n1 = DS * DI / 4, n2 = DOUT * DS / 4, n3 = DOUT * DI / 4;
    if (t < n1) {
        float4 v = ((const float4*)Bm)[t];
        ushort4 o; o.x = f2b(v.x); o.y = f2b(v.y); o.z = f2b(v.z); o.w = f2b(v.w);
        ((ushort4*)Bmb)[t] = o;
    } else if (t < n1 + n2) {
        float4 v = ((const float4*)Cm)[t - n1];
        ushort4 o; o.x = f2b(v.x); o.y = f2b(v.y); o.z = f2b(v.z); o.w = f2b(v.w);
        ((ushort4*)Cmb)[t - n1] = o;
    } else if (t < n1 + n2 + n3) {
        float4 v = ((const float4*)Dm)[t - n1 - n2];
        ushort4 o; o.x = f2b(v.x); o.y = f2b(v.y); o.z = f2b(v.z); o.w = f2b(v.w);
        ((ushort4*)Dmb)[t - n1 - n2] = o;
    }
    if (t < DS) {
        float x = Au[t];
        float sp = (x > 15.f) ? x : log1pf(expf(x));
        float ad = -sp;
        float p = 1.f;
        apow[t] = 1.f;
        for (int j = 1; j <= CT; ++j) { p *= ad; apow[j * DS + t] = p; }
    }
}

// ---------------------------------------------------------------------------
// k_u2t: u[b][i][l] f32 -> u_tr[b][l][i] bf16 (64x64 LDS transpose tiles)
// ---------------------------------------------------------------------------
__global__ __launch_bounds__(256) void k_u2t(const float* __restrict__ u,
                                             ushort* __restrict__ utr) {
    __shared__ float T[64][65];   // stride 65: 2-way max on both phases (free)
    const int tid = threadIdx.x;
    const int l0 = blockIdx.x * 64, i0 = blockIdx.y * 64, b = blockIdx.z;
    const int r = tid >> 4, c4 = tid & 15;
#pragma unroll
    for (int rr = r; rr < 64; rr += 16) {
        float4 v = *(const float4*)&u[((size_t)b * DI + i0 + rr) * LL + l0 + c4 * 4];
        T[rr][c4 * 4 + 0] = v.x; T[rr][c4 * 4 + 1] = v.y;
        T[rr][c4 * 4 + 2] = v.z; T[rr][c4 * 4 + 3] = v.w;
    }
    __syncthreads();
#pragma unroll
    for (int ll = r; ll < 64; ll += 16) {
        ushort4 o;
        o.x = f2b(T[c4 * 4 + 0][ll]); o.y = f2b(T[c4 * 4 + 1][ll]);
        o.z = f2b(T[c4 * 4 + 2][ll]); o.w = f2b(T[c4 * 4 + 3][ll]);
        *(ushort4*)&utr[((size_t)b * LL + l0 + ll) * DI + i0 + c4 * 4] = o;
    }
}

// ---------------------------------------------------------------------------
// k_bu: Xb[l][b][s] (bf16) = sum_i Bm[s][i]*u[b][i][l]
// MFMA 16x16x32 bf16; tile 128(s) x 128(l), BK=32, 4 waves 2x2.
// A-operand = Bm rows (m=s), B-operand = u_tr rows (n=l). D rows = s.
// ---------------------------------------------------------------------------
__global__ __launch_bounds__(256) void k_bu(const ushort* __restrict__ Bmb,
                                            const ushort* __restrict__ utr,
                                            ushort* __restrict__ Xb) {
    __shared__ ushort Abuf[128 * 32];
    __shared__ ushort Bbuf[128 * 32];
    const int tid = threadIdx.x;
    const int w = tid >> 6, lane = tid & 63;
    const int l0 = blockIdx.x * 128, s0 = blockIdx.y * 128, b = blockIdx.z;
    const int wm = w & 1, wn = w >> 1;
    const int mrow = lane & 15, quad = lane >> 4;
    const int sr = lane >> 2, sc = (lane & 3) * 8;

    f32x4 acc[4][4];
#pragma unroll
    for (int mi = 0; mi < 4; ++mi)
#pragma unroll
        for (int ni = 0; ni < 4; ++ni) acc[mi][ni] = (f32x4)0.f;

    const ushort* ag0 = Bmb + (size_t)(s0 + 16 * w + sr) * DI + sc;
    const ushort* ag1 = ag0 + (size_t)64 * DI;
    const ushort* bg0 = utr + ((size_t)b * LL + l0 + 16 * w + sr) * DI + sc;
    const ushort* bg1 = bg0 + (size_t)64 * DI;
    ushort* al0 = &Abuf[(16 * w) * 32];       ushort* al1 = &Abuf[(16 * w + 64) * 32];
    ushort* bl0 = &Bbuf[(16 * w) * 32];       ushort* bl1 = &Bbuf[(16 * w + 64) * 32];

    for (int kk = 0; kk < DI; kk += 32) {
        gload16(ag0 + kk, al0); gload16(ag1 + kk, al1);
        gload16(bg0 + kk, bl0); gload16(bg1 + kk, bl1);
        __syncthreads();
        bf16x8 af[4], bfr[4];
#pragma unroll
        for (int mi = 0; mi < 4; ++mi)
            af[mi] = *(const bf16x8*)&Abuf[(wm * 64 + mi * 16 + mrow) * 32 + quad * 8];
#pragma unroll
        for (int ni = 0; ni < 4; ++ni)
            bfr[ni] = *(const bf16x8*)&Bbuf[(wn * 64 + ni * 16 + mrow) * 32 + quad * 8];
#pragma unroll
        for (int mi = 0; mi < 4; ++mi)
#pragma unroll
            for (int ni = 0; ni < 4; ++ni)
                acc[mi][ni] = __builtin_amdgcn_mfma_f32_16x16x32_bf16(af[mi], bfr[ni], acc[mi][ni], 0, 0, 0);
        __syncthreads();
    }

#pragma unroll
    for (int mi = 0; mi < 4; ++mi) {
        const int s = s0 + wm * 64 + mi * 16 + quad * 4;
#pragma unroll
        for (int ni = 0; ni < 4; ++ni) {
            const int l = l0 + wn * 64 + ni * 16 + mrow;
            f32x4 v = acc[mi][ni];
            ushort4 o; o.x = f2b(v[0]); o.y = f2b(v[1]); o.z = f2b(v[2]); o.w = f2b(v[3]);
            *(ushort4*)&Xb[(size_t)l * BS + (size_t)b * DS + s] = o;
        }
    }
}

// ---------------------------------------------------------------------------
// k_scan: per-chunk zero-init scan, in place on Xb (bf16), fp32 accumulator
// ---------------------------------------------------------------------------
__global__ __launch_bounds__(256) void k_scan(ushort* __restrict__ Xb,
                                              float* __restrict__ finals,
                                              const float* __restrict__ apow) {
    const int c = blockIdx.x;
    const int bs = blockIdx.y * 256 + threadIdx.x;
    const int s = bs & (DS - 1);
    const float a = apow[DS + s];
    float acc = 0.f;
    ushort* p = Xb + (size_t)c * CT * BS + bs;
#pragma unroll 4
    for (int j = 0; j < CT; ++j) {
        acc = acc * a + b2f(*p);
        *p = f2b(acc);
        p += BS;
    }
    finals[(size_t)c * BS + bs] = acc;
}

// ---------------------------------------------------------------------------
// k_carry: sequential scan over 64 chunk carries (fp32)
// ---------------------------------------------------------------------------
__global__ __launch_bounds__(256) void k_carry(const float* __restrict__ finals,
                                               float* __restrict__ carries,
                                               const float* __restrict__ apow,
                                               const float* __restrict__ h0) {
    const int bs = blockIdx.x * 256 + threadIdx.x;
    const int s = bs & (DS - 1);
    const float aT = apow[CT * DS + s];
    float carry = h0[s];
    for (int c = 0; c < CH; ++c) {
        carries[(size_t)c * BS + bs] = carry;
        carry = aT * carry + finals[(size_t)c * BS + bs];
    }
}

// ---------------------------------------------------------------------------
// k_correct: Xb += a^{j+1} * carry  (in place, bf16, 8 elems/thread)
// ---------------------------------------------------------------------------
__global__ __launch_bounds__(256) void k_correct(ushort* __restrict__ Xb,
                                                 const float* __restrict__ carries,
                                                 const float* __restrict__ apow) {
    const size_t i8 = (size_t)blockIdx.x * 256 + threadIdx.x;
    const size_t base = i8 * 8;
    const int t = (int)(base >> 12);
    const int bs0 = (int)(base & (BS - 1));
    const int c = t >> 6, j = t & (CT - 1);
    const int s0 = bs0 & (DS - 1);
    ushort4 xa = *(ushort4*)&Xb[base];
    ushort4 xb = *(ushort4*)&Xb[base + 4];
    float4 ca = *(const float4*)&carries[(size_t)c * BS + bs0];
    float4 cb = *(const float4*)&carries[(size_t)c * BS + bs0 + 4];
    const float* ap = &apow[(size_t)(j + 1) * DS + s0];
    float4 pa = *(const float4*)ap;
    float4 pb = *(const float4*)(ap + 4);
    ushort4 oa, ob;
    oa.x = f2b(b2f(xa.x) + pa.x * ca.x); oa.y = f2b(b2f(xa.y) + pa.y * ca.y);
    oa.z = f2b(b2f(xa.z) + pa.z * ca.z); oa.w = f2b(b2f(xa.w) + pa.w * ca.w);
    ob.x = f2b(b2f(xb.x) + pb.x * cb.x); ob.y = f2b(b2f(xb.y) + pb.y * cb.y);
    ob.z = f2b(b2f(xb.z) + pb.z * cb.z); ob.w = f2b(b2f(xb.w) + pb.w * cb.w);
    *(ushort4*)&Xb[base] = oa;
    *(ushort4*)&Xb[base + 4] = ob;
}

// ---------------------------------------------------------------------------
// k_out: Y[b][o][l] f32 = sum_s C[o][s]*X[l][b][s] + sum_i D[o][i]*u[b][i][l]
// MFMA; tile 128(l) x 128(o); A-operand = X/u_tr rows (m=l), B = C/D rows (n=o)
// ---------------------------------------------------------------------------
__global__ __launch_bounds__(256) void k_out(const ushort* __restrict__ Cmb,
                                             const ushort* __restrict__ Dmb,
                                             const ushort* __restrict__ Xb,
                                             const ushort* __restrict__ utr,
                                             float* __restrict__ Y) {
    __shared__ ushort Abuf[128 * 32];
    __shared__ ushort Bbuf[128 * 32];
    const int tid = threadIdx.x;
    const int w = tid >> 6, lane = tid & 63;
    const int l0 = blockIdx.x * 128, o0 = blockIdx.y * 128, b = blockIdx.z;
    const int wm = w & 1, wn = w >> 1;
    const int mrow = lane & 15, quad = lane >> 4;
    const int sr = lane >> 2, sc = (lane & 3) * 8;

    f32x4 acc[4][4];
#pragma unroll
    for (int mi = 0; mi < 4; ++mi)
#pragma unroll
        for (int ni = 0; ni < 4; ++ni) acc[mi][ni] = (f32x4)0.f;

    ushort* al0 = &Abuf[(16 * w) * 32];       ushort* al1 = &Abuf[(16 * w + 64) * 32];
    ushort* bl0 = &Bbuf[(16 * w) * 32];       ushort* bl1 = &Bbuf[(16 * w + 64) * 32];

    auto compute = [&]() {
        bf16x8 af[4], bfr[4];
#pragma unroll
        for (int mi = 0; mi < 4; ++mi)
            af[mi] = *(const bf16x8*)&Abuf[(wm * 64 + mi * 16 + mrow) * 32 + quad * 8];
#pragma unroll
        for (int ni = 0; ni < 4; ++ni)
            bfr[ni] = *(const bf16x8*)&Bbuf[(wn * 64 + ni * 16 + mrow) * 32 + quad * 8];
#pragma unroll
        for (int mi = 0; mi < 4; ++mi)
#pragma unroll
            for (int ni = 0; ni < 4; ++ni)
                acc[mi][ni] = __builtin_amdgcn_mfma_f32_16x16x32_bf16(af[mi], bfr[ni], acc[mi][ni], 0, 0, 0);
    };

    { // phase 1: C @ X, K = DS
        const ushort* ag0 = Xb + (size_t)(l0 + 16 * w + sr) * BS + (size_t)b * DS + sc;
        const ushort* ag1 = ag0 + (size_t)64 * BS;
        const ushort* bg0 = Cmb + (size_t)(o0 + 16 * w + sr) * DS + sc;
        const ushort* bg1 = bg0 + (size_t)64 * DS;
        for (int kk = 0; kk < DS; kk += 32) {
            gload16(ag0 + kk, al0); gload16(ag1 + kk, al1);
            gload16(bg0 + kk, bl0); gload16(bg1 + kk, bl1);
            __syncthreads();
            compute();
            __syncthreads();
        }
    }
    { // phase 2: D @ u, K = DI
        const ushort* ag0 = utr + ((size_t)b * LL + l0 + 16 * w + sr) * DI + sc;
        const ushort* ag1 = ag0 + (size_t)64 * DI;
        const ushort* bg0 = Dmb + (size_t)(o0 + 16 * w + sr) * DI + sc;
        const ushort* bg1 = bg0 + (size_t)64 * DI;
        for (int kk = 0; kk < DI; kk += 32) {
            gload16(ag0 + kk, al0); gload16(ag1 + kk, al1);
            gload16(bg0 + kk, bl0); gload16(bg1 + kk, bl1);
            __syncthreads();
            compute();
            __syncthreads();
        }
    }

#pragma unroll
    for (int mi = 0; mi < 4; ++mi) {
        const int l = l0 + wm * 64 + mi * 16 + quad * 4;
#pragma unroll
        for (int ni = 0; ni < 4; ++ni) {
            const int o = o0 + wn * 64 + ni * 16 + mrow;
            *(float4*)&Y[((size_t)b * DOUT + o) * LL + l] = *(float4*)&acc[mi][ni];
        }
    }
}

// ---------------------------------------------------------------------------
extern "C" void kernel_launch(void* const* d_in, const int* in_sizes, int n_in,
                              void* d_out, int out_size, void* d_ws, size_t ws_size,
                              hipStream_t stream) {
    const float* u  = (const float*)d_in[0];
    const float* Au = (const float*)d_in[1];
    const float* Bm = (const float*)d_in[2];
    const float* Cm = (const float*)d_in[3];
    const float* Dm = (const float*)d_in[4];
    const float* h0 = (const float*)d_in[5];
    float* Y = (float*)d_out;

    char* p = (char*)d_ws;
    ushort* utr    = (ushort*)p; p += (size_t)BZ * LL * DI * 2;   // 16 MB
    ushort* Xb     = (ushort*)p; p += (size_t)LL * BS * 2;        // 33.5 MB
    float* finals  = (float*)p;  p += (size_t)CH * BS * 4;        // 1 MB
    float* carries = (float*)p;  p += (size_t)CH * BS * 4;        // 1 MB
    float* apow    = (float*)p;  p += (size_t)(CT + 1) * DS * 4;
    ushort* Bmb    = (ushort*)p; p += (size_t)DS * DI * 2;
    ushort* Cmb    = (ushort*)p; p += (size_t)DOUT * DS * 2;
    ushort* Dmb    = (ushort*)p; p += (size_t)DOUT * DI * 2;

    k_prep<<<dim3(320), 256, 0, stream>>>(Au, apow, Bm, Cm, Dm, Bmb, Cmb, Dmb);
    k_u2t<<<dim3(LL / 64, DI / 64, BZ), 256, 0, stream>>>(u, utr);
    k_bu<<<dim3(LL / 128, DS / 128, BZ), 256, 0, stream>>>(Bmb, utr, Xb);
    k_scan<<<dim3(CH, BS / 256), 256, 0, stream>>>(Xb, finals, apow);
    k_carry<<<dim3(BS / 256), 256, 0, stream>>>(finals, carries, apow, h0);
    k_correct<<<dim3((int)(((size_t)LL * BS) / 8 / 256)), 256, 0, stream>>>(Xb, carries, apow);
    k_out<<<dim3(LL / 128, DOUT / 128, BZ), 256, 0, stream>>>(Cmb, Dmb, Xb, utr, Y);
}

// Round 4
// 149.704 us; speedup vs baseline: 2.7985x; 1.1266x over previous
//
#include <hip/hip_runtime.h>
#include <math.h>

// SimpleSSM: u(B,DI,L) f32, A(S), B_mat(S,DI), C_mat(DO,S), D_mat(DO,DI), h0(S)
#define BZ 8
#define DI 256
#define DS 512
#define DOUT 256
#define LL 4096
#define BS (BZ * DS)   // 4096
#define CH 64
#define CT 64
#define TST 136        // k_bu scan-tile LDS stride in ushorts (272B: 16B-aligned, banks OK)

typedef __bf16 bf16x8 __attribute__((ext_vector_type(8)));
typedef float f32x4 __attribute__((ext_vector_type(4)));
typedef unsigned short us8 __attribute__((ext_vector_type(8)));

__device__ __forceinline__ ushort f2b(float f) {
    union { float f; unsigned u; } v; v.f = f;
    unsigned r = v.u + 0x7FFFu + ((v.u >> 16) & 1u);
    return (ushort)(r >> 16);
}
__device__ __forceinline__ float b2f(ushort h) {
    union { unsigned u; float f; } v; v.u = ((unsigned)h) << 16;
    return v.f;
}

// async 16B global->LDS (dst = wave-uniform base + lane*16; global addr per-lane)
__device__ __forceinline__ void gload16(const ushort* g, ushort* l) {
    __builtin_amdgcn_global_load_lds(
        (const __attribute__((address_space(1))) unsigned int*)g,
        (__attribute__((address_space(3))) unsigned int*)l,
        16, 0, 0);
}

// ---------------------------------------------------------------------------
// k_prep: apow[j][s]=a^j (a=-softplus), bf16 conversion of Bm/Cm/Dm
// ---------------------------------------------------------------------------
__global__ __launch_bounds__(256) void k_prep(const float* __restrict__ Au,
                                              float* __restrict__ apow,
                                              const float* __restrict__ Bm,
                                              const float* __restrict__ Cm,
                                              const float* __restrict__ Dm,
                                              ushort* __restrict__ Bmb,
                                              ushort* __restrict__ Cmb,
                                              ushort* __restrict__ Dmb) {
    const int t = blockIdx.x * 256 + threadIdx.x;
    const int n1 = DS * DI / 4, n2 = DOUT * DS / 4, n3 = DOUT * DI / 4;
    if (t < n1) {
        float4 v = ((const float4*)Bm)[t];
        ushort4 o; o.x = f2b(v.x); o.y = f2b(v.y); o.z = f2b(v.z); o.w = f2b(v.w);
        ((ushort4*)Bmb)[t] = o;
    } else if (t < n1 + n2) {
        float4 v = ((const float4*)Cm)[t - n1];
        ushort4 o; o.x = f2b(v.x); o.y = f2b(v.y); o.z = f2b(v.z); o.w = f2b(v.w);
        ((ushort4*)Cmb)[t - n1] = o;
    } else if (t < n1 + n2 + n3) {
        float4 v = ((const float4*)Dm)[t - n1 - n2];
        ushort4 o; o.x = f2b(v.x); o.y = f2b(v.y); o.z = f2b(v.z); o.w = f2b(v.w);
        ((ushort4*)Dmb)[t - n1 - n2] = o;
    }
    if (t < DS) {
        float x = Au[t];
        float sp = (x > 15.f) ? x : log1pf(expf(x));
        float ad = -sp;
        float p = 1.f;
        apow[t] = 1.f;
        for (int j = 1; j <= CT; ++j) { p *= ad; apow[j * DS + t] = p; }
    }
}

// ---------------------------------------------------------------------------
// k_u2t: u[b][i][l] f32 -> u_tr[b][l][i] bf16 (64x64 LDS transpose tiles)
// ---------------------------------------------------------------------------
__global__ __launch_bounds__(256) void k_u2t(const float* __restrict__ u,
                                             ushort* __restrict__ utr) {
    __shared__ float T[64][65];
    const int tid = threadIdx.x;
    const int l0 = blockIdx.x * 64, i0 = blockIdx.y * 64, b = blockIdx.z;
    const int r = tid >> 4, c4 = tid & 15;
#pragma unroll
    for (int rr = r; rr < 64; rr += 16) {
        float4 v = *(const float4*)&u[((size_t)b * DI + i0 + rr) * LL + l0 + c4 * 4];
        T[rr][c4 * 4 + 0] = v.x; T[rr][c4 * 4 + 1] = v.y;
        T[rr][c4 * 4 + 2] = v.z; T[rr][c4 * 4 + 3] = v.w;
    }
    __syncthreads();
#pragma unroll
    for (int ll = r; ll < 64; ll += 16) {
        ushort4 o;
        o.x = f2b(T[c4 * 4 + 0][ll]); o.y = f2b(T[c4 * 4 + 1][ll]);
        o.z = f2b(T[c4 * 4 + 2][ll]); o.w = f2b(T[c4 * 4 + 3][ll]);
        *(ushort4*)&utr[((size_t)b * LL + l0 + ll) * DI + i0 + c4 * 4] = o;
    }
}

// ---------------------------------------------------------------------------
// k_bu: Xb[l][b][s] = local-scanned(sum_i Bm[s][i]*u[b][i][l]); also finals.
// MFMA tile 128(s) x 128(l); epilogue does the 2-chunk local scan in LDS.
// ---------------------------------------------------------------------------
__global__ __launch_bounds__(256) void k_bu(const ushort* __restrict__ Bmb,
                                            const ushort* __restrict__ utr,
                                            ushort* __restrict__ Xb,
                                            float* __restrict__ finals,
                                            const float* __restrict__ apow) {
    __shared__ ushort smem[128 * TST];        // 34.8 KB; first 16 KB doubles as GEMM bufs
    ushort* Abuf = smem;                      // 128 x 32
    ushort* Bbuf = smem + 128 * 32;           // 128 x 32
    const int tid = threadIdx.x;
    const int w = tid >> 6, lane = tid & 63;
    const int l0 = blockIdx.x * 128, s0 = blockIdx.y * 128, b = blockIdx.z;
    const int wm = w & 1, wn = w >> 1;
    const int mrow = lane & 15, quad = lane >> 4;
    const int sr = lane >> 2, sc = (lane & 3) * 8;

    f32x4 acc[4][4];
#pragma unroll
    for (int mi = 0; mi < 4; ++mi)
#pragma unroll
        for (int ni = 0; ni < 4; ++ni) acc[mi][ni] = (f32x4)0.f;

    const ushort* ag0 = Bmb + (size_t)(s0 + 16 * w + sr) * DI + sc;
    const ushort* ag1 = ag0 + (size_t)64 * DI;
    const ushort* bg0 = utr + ((size_t)b * LL + l0 + 16 * w + sr) * DI + sc;
    const ushort* bg1 = bg0 + (size_t)64 * DI;
    ushort* al0 = &Abuf[(16 * w) * 32];       ushort* al1 = &Abuf[(16 * w + 64) * 32];
    ushort* bl0 = &Bbuf[(16 * w) * 32];       ushort* bl1 = &Bbuf[(16 * w + 64) * 32];

    for (int kk = 0; kk < DI; kk += 32) {
        gload16(ag0 + kk, al0); gload16(ag1 + kk, al1);
        gload16(bg0 + kk, bl0); gload16(bg1 + kk, bl1);
        __syncthreads();
        bf16x8 af[4], bfr[4];
#pragma unroll
        for (int mi = 0; mi < 4; ++mi)
            af[mi] = *(const bf16x8*)&Abuf[(wm * 64 + mi * 16 + mrow) * 32 + quad * 8];
#pragma unroll
        for (int ni = 0; ni < 4; ++ni)
            bfr[ni] = *(const bf16x8*)&Bbuf[(wn * 64 + ni * 16 + mrow) * 32 + quad * 8];
#pragma unroll
        for (int mi = 0; mi < 4; ++mi)
#pragma unroll
            for (int ni = 0; ni < 4; ++ni)
                acc[mi][ni] = __builtin_amdgcn_mfma_f32_16x16x32_bf16(af[mi], bfr[ni], acc[mi][ni], 0, 0, 0);
        __syncthreads();
    }

    // ---- epilogue: acc -> LDS tile T[l][s] (stride TST), local scan, write out
#pragma unroll
    for (int mi = 0; mi < 4; ++mi) {
        const int sloc = wm * 64 + mi * 16 + quad * 4;
#pragma unroll
        for (int ni = 0; ni < 4; ++ni) {
            const int lloc = wn * 64 + ni * 16 + mrow;
            f32x4 v = acc[mi][ni];
            ushort4 o; o.x = f2b(v[0]); o.y = f2b(v[1]); o.z = f2b(v[2]); o.w = f2b(v[3]);
            *(ushort4*)&smem[lloc * TST + sloc] = o;
        }
    }
    __syncthreads();
    {   // local scan: thread = (chunk-local cloc, s-local sl); 64 sequential steps in LDS
        const int cloc = tid >> 7, sl = tid & 127;
        const float a = apow[DS + s0 + sl];
        float acc2 = 0.f;
        ushort* p = &smem[(cloc * 64) * TST + sl];
#pragma unroll 8
        for (int j = 0; j < CT; ++j) {
            acc2 = a * acc2 + b2f(*p);
            *p = f2b(acc2);
            p += TST;
        }
        finals[(size_t)(l0 / 64 + cloc) * BS + (size_t)b * DS + s0 + sl] = acc2;
    }
    __syncthreads();
    {   // coalesced tile write
        const int rr = tid >> 4, cc = tid & 15;
#pragma unroll
        for (int rep = 0; rep < 8; ++rep) {
            const int l = rep * 16 + rr;
            us8 v = *(const us8*)&smem[l * TST + cc * 8];
            *(us8*)&Xb[(size_t)(l0 + l) * BS + (size_t)b * DS + s0 + cc * 8] = v;
        }
    }
}

// ---------------------------------------------------------------------------
// k_carry: sequential scan over 64 chunk carries (fp32)
// ---------------------------------------------------------------------------
__global__ __launch_bounds__(256) void k_carry(const float* __restrict__ finals,
                                               float* __restrict__ carries,
                                               const float* __restrict__ apow,
                                               const float* __restrict__ h0) {
    const int bs = blockIdx.x * 256 + threadIdx.x;
    const int s = bs & (DS - 1);
    const float aT = apow[CT * DS + s];
    float carry = h0[s];
    for (int c = 0; c < CH; ++c) {
        carries[(size_t)c * BS + bs] = carry;
        carry = aT * carry + finals[(size_t)c * BS + bs];
    }
}

// ---------------------------------------------------------------------------
// k_out: Y[b][o][l] f32 = sum_s C[o][s]*(X[l][b][s] + a^{j+1} carry) + sum_i D[o][i]*u[b][i][l]
// Phase-1 A staged through VGPRs with the carry correction fused in.
// ---------------------------------------------------------------------------
__global__ __launch_bounds__(256) void k_out(const ushort* __restrict__ Cmb,
                                             const ushort* __restrict__ Dmb,
                                             const ushort* __restrict__ Xb,
                                             const ushort* __restrict__ utr,
                                             const float* __restrict__ carries,
                                             const float* __restrict__ apow,
                                             float* __restrict__ Y) {
    __shared__ ushort Apad[128 * 40];   // phase-1 A, padded stride 40
    __shared__ ushort Bbuf[128 * 32];
    const int tid = threadIdx.x;
    const int w = tid >> 6, lane = tid & 63;
    const int l0 = blockIdx.x * 128, o0 = blockIdx.y * 128, b = blockIdx.z;
    const int wm = w & 1, wn = w >> 1;
    const int mrow = lane & 15, quad = lane >> 4;
    const int sr = lane >> 2, sc = (lane & 3) * 8;

    f32x4 acc[4][4];
#pragma unroll
    for (int mi = 0; mi < 4; ++mi)
#pragma unroll
        for (int ni = 0; ni < 4; ++ni) acc[mi][ni] = (f32x4)0.f;

    auto compute = [&](const ushort* Ab, const int ast) {
        bf16x8 af[4], bfr[4];
#pragma unroll
        for (int mi = 0; mi < 4; ++mi)
            af[mi] = *(const bf16x8*)&Ab[(wm * 64 + mi * 16 + mrow) * ast + quad * 8];
#pragma unroll
        for (int ni = 0; ni < 4; ++ni)
            bfr[ni] = *(const bf16x8*)&Bbuf[(wn * 64 + ni * 16 + mrow) * 32 + quad * 8];
#pragma unroll
        for (int mi = 0; mi < 4; ++mi)
#pragma unroll
            for (int ni = 0; ni < 4; ++ni)
                acc[mi][ni] = __builtin_amdgcn_mfma_f32_16x16x32_bf16(af[mi], bfr[ni], acc[mi][ni], 0, 0, 0);
    };

    { // phase 1: C @ X_corrected, K = DS
        const int r0 = 16 * w + sr;           // 0..63
        const int l_0 = l0 + r0, l_1 = l_0 + 64;
        const int j0 = l_0 & 63, c0 = l_0 >> 6;
        const int j1 = l_1 & 63, c1 = l_1 >> 6;
        const float* ap0 = &apow[(size_t)(j0 + 1) * DS];
        const float* ap1 = &apow[(size_t)(j1 + 1) * DS];
        const float* cr0 = &carries[(size_t)c0 * BS + (size_t)b * DS];
        const float* cr1 = &carries[(size_t)c1 * BS + (size_t)b * DS];
        const ushort* x0 = Xb + (size_t)l_0 * BS + (size_t)b * DS;
        const ushort* x1 = Xb + (size_t)l_1 * BS + (size_t)b * DS;
        const ushort* bg0 = Cmb + (size_t)(o0 + r0) * DS + sc;   // FIX: + sc (per-lane col)
        const ushort* bg1 = bg0 + (size_t)64 * DS;
        ushort* bl0 = &Bbuf[(16 * w) * 32];
        ushort* bl1 = &Bbuf[(16 * w + 64) * 32];
        for (int kk = 0; kk < DS; kk += 32) {
            const int col = kk + sc;
            gload16(bg0 + kk, bl0); gload16(bg1 + kk, bl1);
            // A-staging half 0 with correction
            {
                us8 x = *(const us8*)&x0[col];
                float4 pa = *(const float4*)&ap0[col], pb = *(const float4*)&ap0[col + 4];
                float4 ca = *(const float4*)&cr0[col], cb = *(const float4*)&cr0[col + 4];
                us8 o;
                o[0] = f2b(b2f(x[0]) + pa.x * ca.x); o[1] = f2b(b2f(x[1]) + pa.y * ca.y);
                o[2] = f2b(b2f(x[2]) + pa.z * ca.z); o[3] = f2b(b2f(x[3]) + pa.w * ca.w);
                o[4] = f2b(b2f(x[4]) + pb.x * cb.x); o[5] = f2b(b2f(x[5]) + pb.y * cb.y);
                o[6] = f2b(b2f(x[6]) + pb.z * cb.z); o[7] = f2b(b2f(x[7]) + pb.w * cb.w);
                *(us8*)&Apad[r0 * 40 + sc] = o;
            }
            // A-staging half 1
            {
                us8 x = *(const us8*)&x1[col];
                float4 pa = *(const float4*)&ap1[col], pb = *(const float4*)&ap1[col + 4];
                float4 ca = *(const float4*)&cr1[col], cb = *(const float4*)&cr1[col + 4];
                us8 o;
                o[0] = f2b(b2f(x[0]) + pa.x * ca.x); o[1] = f2b(b2f(x[1]) + pa.y * ca.y);
                o[2] = f2b(b2f(x[2]) + pa.z * ca.z); o[3] = f2b(b2f(x[3]) + pa.w * ca.w);
                o[4] = f2b(b2f(x[4]) + pb.x * cb.x); o[5] = f2b(b2f(x[5]) + pb.y * cb.y);
                o[6] = f2b(b2f(x[6]) + pb.z * cb.z); o[7] = f2b(b2f(x[7]) + pb.w * cb.w);
                *(us8*)&Apad[(r0 + 64) * 40 + sc] = o;
            }
            __syncthreads();
            compute(Apad, 40);
            __syncthreads();
        }
    }
    { // phase 2: D @ u, K = DI (pure gload16 staging, stride 32 in Apad region)
        const ushort* ag0 = utr + ((size_t)b * LL + l0 + 16 * w + sr) * DI + sc;
        const ushort* ag1 = ag0 + (size_t)64 * DI;
        const ushort* bg0 = Dmb + (size_t)(o0 + 16 * w + sr) * DI + sc;
        const ushort* bg1 = bg0 + (size_t)64 * DI;
        ushort* al0 = &Apad[(16 * w) * 32];       ushort* al1 = &Apad[(16 * w + 64) * 32];
        ushort* bl0 = &Bbuf[(16 * w) * 32];       ushort* bl1 = &Bbuf[(16 * w + 64) * 32];
        for (int kk = 0; kk < DI; kk += 32) {
            gload16(ag0 + kk, al0); gload16(ag1 + kk, al1);
            gload16(bg0 + kk, bl0); gload16(bg1 + kk, bl1);
            __syncthreads();
            compute(Apad, 32);
            __syncthreads();
        }
    }

#pragma unroll
    for (int mi = 0; mi < 4; ++mi) {
        const int l = l0 + wm * 64 + mi * 16 + quad * 4;
#pragma unroll
        for (int ni = 0; ni < 4; ++ni) {
            const int o = o0 + wn * 64 + ni * 16 + mrow;
            *(float4*)&Y[((size_t)b * DOUT + o) * LL + l] = *(float4*)&acc[mi][ni];
        }
    }
}

// ---------------------------------------------------------------------------
extern "C" void kernel_launch(void* const* d_in, const int* in_sizes, int n_in,
                              void* d_out, int out_size, void* d_ws, size_t ws_size,
                              hipStream_t stream) {
    const float* u  = (const float*)d_in[0];
    const float* Au = (const float*)d_in[1];
    const float* Bm = (const float*)d_in[2];
    const float* Cm = (const float*)d_in[3];
    const float* Dm = (const float*)d_in[4];
    const float* h0 = (const float*)d_in[5];
    float* Y = (float*)d_out;

    char* p = (char*)d_ws;
    ushort* utr    = (ushort*)p; p += (size_t)BZ * LL * DI * 2;   // 16.8 MB
    ushort* Xb     = (ushort*)p; p += (size_t)LL * BS * 2;        // 33.5 MB
    float* finals  = (float*)p;  p += (size_t)CH * BS * 4;        // 1 MB
    float* carries = (float*)p;  p += (size_t)CH * BS * 4;        // 1 MB
    float* apow    = (float*)p;  p += (size_t)(CT + 1) * DS * 4;
    ushort* Bmb    = (ushort*)p; p += (size_t)DS * DI * 2;
    ushort* Cmb    = (ushort*)p; p += (size_t)DOUT * DS * 2;
    ushort* Dmb    = (ushort*)p; p += (size_t)DOUT * DI * 2;

    k_prep<<<dim3(320), 256, 0, stream>>>(Au, apow, Bm, Cm, Dm, Bmb, Cmb, Dmb);
    k_u2t<<<dim3(LL / 64, DI / 64, BZ), 256, 0, stream>>>(u, utr);
    k_bu<<<dim3(LL / 128, DS / 128, BZ), 256, 0, stream>>>(Bmb, utr, Xb, finals, apow);
    k_carry<<<dim3(BS / 256), 256, 0, stream>>>(finals, carries, apow, h0);
    k_out<<<dim3(LL / 128, DOUT / 128, BZ), 256, 0, stream>>>(Cmb, Dmb, Xb, utr, carries, apow, Y);
}

// Round 6
// 147.534 us; speedup vs baseline: 2.8396x; 1.0147x over previous
//
#include <hip/hip_runtime.h>
#include <math.h>

// SimpleSSM: u(B,DI,L) f32, A(S), B_mat(S,DI), C_mat(DO,S), D_mat(DO,DI), h0(S)
#define BZ 8
#define DI 256
#define DS 512
#define DOUT 256
#define LL 4096
#define BS (BZ * DS)   // 4096
#define CH 64
#define CT 64
#define TST 136        // k_bu scan-tile LDS stride in ushorts

typedef __bf16 bf16x8 __attribute__((ext_vector_type(8)));
typedef float f32x4 __attribute__((ext_vector_type(4)));
typedef unsigned short us8 __attribute__((ext_vector_type(8)));

__device__ __forceinline__ ushort f2b(float f) {
    union { float f; unsigned u; } v; v.f = f;
    unsigned r = v.u + 0x7FFFu + ((v.u >> 16) & 1u);
    return (ushort)(r >> 16);
}
__device__ __forceinline__ float b2f(ushort h) {
    union { unsigned u; float f; } v; v.u = ((unsigned)h) << 16;
    return v.f;
}

__device__ __forceinline__ void gload16(const ushort* g, ushort* l) {
    __builtin_amdgcn_global_load_lds(
        (const __attribute__((address_space(1))) unsigned int*)g,
        (__attribute__((address_space(3))) unsigned int*)l,
        16, 0, 0);
}

// ---------------------------------------------------------------------------
__global__ __launch_bounds__(256) void k_prep(const float* __restrict__ Au,
                                              float* __restrict__ apow,
                                              const float* __restrict__ Bm,
                                              const float* __restrict__ Cm,
                                              const float* __restrict__ Dm,
                                              ushort* __restrict__ Bmb,
                                              ushort* __restrict__ Cmb,
                                              ushort* __restrict__ Dmb) {
    const int t = blockIdx.x * 256 + threadIdx.x;
    const int n1 = DS * DI / 4, n2 = DOUT * DS / 4, n3 = DOUT * DI / 4;
    if (t < n1) {
        float4 v = ((const float4*)Bm)[t];
        ushort4 o; o.x = f2b(v.x); o.y = f2b(v.y); o.z = f2b(v.z); o.w = f2b(v.w);
        ((ushort4*)Bmb)[t] = o;
    } else if (t < n1 + n2) {
        float4 v = ((const float4*)Cm)[t - n1];
        ushort4 o; o.x = f2b(v.x); o.y = f2b(v.y); o.z = f2b(v.z); o.w = f2b(v.w);
        ((ushort4*)Cmb)[t - n1] = o;
    } else if (t < n1 + n2 + n3) {
        float4 v = ((const float4*)Dm)[t - n1 - n2];
        ushort4 o; o.x = f2b(v.x); o.y = f2b(v.y); o.z = f2b(v.z); o.w = f2b(v.w);
        ((ushort4*)Dmb)[t - n1 - n2] = o;
    }
    if (t < DS) {
        float x = Au[t];
        float sp = (x > 15.f) ? x : log1pf(expf(x));
        float ad = -sp;
        float p = 1.f;
        apow[t] = 1.f;
        for (int j = 1; j <= CT; ++j) { p *= ad; apow[j * DS + t] = p; }
    }
}

// ---------------------------------------------------------------------------
__global__ __launch_bounds__(256) void k_u2t(const float* __restrict__ u,
                                             ushort* __restrict__ utr) {
    __shared__ float T[64][65];
    const int tid = threadIdx.x;
    const int l0 = blockIdx.x * 64, i0 = blockIdx.y * 64, b = blockIdx.z;
    const int r = tid >> 4, c4 = tid & 15;
#pragma unroll
    for (int rr = r; rr < 64; rr += 16) {
        float4 v = *(const float4*)&u[((size_t)b * DI + i0 + rr) * LL + l0 + c4 * 4];
        T[rr][c4 * 4 + 0] = v.x; T[rr][c4 * 4 + 1] = v.y;
        T[rr][c4 * 4 + 2] = v.z; T[rr][c4 * 4 + 3] = v.w;
    }
    __syncthreads();
#pragma unroll
    for (int ll = r; ll < 64; ll += 16) {
        ushort4 o;
        o.x = f2b(T[c4 * 4 + 0][ll]); o.y = f2b(T[c4 * 4 + 1][ll]);
        o.z = f2b(T[c4 * 4 + 2][ll]); o.w = f2b(T[c4 * 4 + 3][ll]);
        *(ushort4*)&utr[((size_t)b * LL + l0 + ll) * DI + i0 + c4 * 4] = o;
    }
}

// ---------------------------------------------------------------------------
// k_bu: Xb = local-scanned(B @ u) + finals. Single-barrier dbuf K-loop.
// LDS buffers selected by integer offsets (no LDS pointer arrays on gfx950).
// ---------------------------------------------------------------------------
__global__ __launch_bounds__(256) void k_bu(const ushort* __restrict__ Bmb,
                                            const ushort* __restrict__ utr,
                                            ushort* __restrict__ Xb,
                                            float* __restrict__ finals,
                                            const float* __restrict__ apow) {
    __shared__ ushort smem[128 * TST];   // 34.8 KB; GEMM dbuf = first 32 KB
    // A buffers at 0 / 4096, B buffers at 8192 / 12288 (ushort offsets)
    const int tid = threadIdx.x;
    const int w = tid >> 6, lane = tid & 63;
    const int l0 = blockIdx.x * 128, s0 = blockIdx.y * 128, b = blockIdx.z;
    const int wm = w & 1, wn = w >> 1;
    const int mrow = lane & 15, quad = lane >> 4;
    const int sr = lane >> 2, sc = (lane & 3) * 8;
    const int off0 = (16 * w) * 32, off1 = (16 * w + 64) * 32;

    f32x4 acc[4][4];
#pragma unroll
    for (int mi = 0; mi < 4; ++mi)
#pragma unroll
        for (int ni = 0; ni < 4; ++ni) acc[mi][ni] = (f32x4)0.f;

    const ushort* ag0 = Bmb + (size_t)(s0 + 16 * w + sr) * DI + sc;
    const ushort* ag1 = ag0 + (size_t)64 * DI;
    const ushort* bg0 = utr + ((size_t)b * LL + l0 + 16 * w + sr) * DI + sc;
    const ushort* bg1 = bg0 + (size_t)64 * DI;

    // prologue: stage iter 0 into buffer 0
    gload16(ag0, smem + off0); gload16(ag1, smem + off1);
    gload16(bg0, smem + 8192 + off0); gload16(bg1, smem + 8192 + off1);

    for (int it = 0; it < DI / 32; ++it) {
        __syncthreads();                      // drains prev prefetch, fences LDS reuse
        const int cb = (it & 1) * 4096, nb = 4096 - cb;
        if (it + 1 < DI / 32) {
            const int kk = (it + 1) * 32;
            gload16(ag0 + kk, smem + nb + off0); gload16(ag1 + kk, smem + nb + off1);
            gload16(bg0 + kk, smem + 8192 + nb + off0); gload16(bg1 + kk, smem + 8192 + nb + off1);
        }
        bf16x8 af[4], bfr[4];
#pragma unroll
        for (int mi = 0; mi < 4; ++mi)
            af[mi] = *(const bf16x8*)&smem[cb + (wm * 64 + mi * 16 + mrow) * 32 + quad * 8];
#pragma unroll
        for (int ni = 0; ni < 4; ++ni)
            bfr[ni] = *(const bf16x8*)&smem[8192 + cb + (wn * 64 + ni * 16 + mrow) * 32 + quad * 8];
#pragma unroll
        for (int mi = 0; mi < 4; ++mi)
#pragma unroll
            for (int ni = 0; ni < 4; ++ni)
                acc[mi][ni] = __builtin_amdgcn_mfma_f32_16x16x32_bf16(af[mi], bfr[ni], acc[mi][ni], 0, 0, 0);
    }
    __syncthreads();

    // epilogue: acc -> LDS tile [l][s] (stride TST), local scan, coalesced write
#pragma unroll
    for (int mi = 0; mi < 4; ++mi) {
        const int sloc = wm * 64 + mi * 16 + quad * 4;
#pragma unroll
        for (int ni = 0; ni < 4; ++ni) {
            const int lloc = wn * 64 + ni * 16 + mrow;
            f32x4 v = acc[mi][ni];
            ushort4 o; o.x = f2b(v[0]); o.y = f2b(v[1]); o.z = f2b(v[2]); o.w = f2b(v[3]);
            *(ushort4*)&smem[lloc * TST + sloc] = o;
        }
    }
    __syncthreads();
    {
        const int cloc = tid >> 7, sl = tid & 127;
        const float a = apow[DS + s0 + sl];
        float acc2 = 0.f;
        ushort* p = &smem[(cloc * 64) * TST + sl];
#pragma unroll 8
        for (int j = 0; j < CT; ++j) {
            acc2 = a * acc2 + b2f(*p);
            *p = f2b(acc2);
            p += TST;
        }
        finals[(size_t)(l0 / 64 + cloc) * BS + (size_t)b * DS + s0 + sl] = acc2;
    }
    __syncthreads();
    {
        const int rr = tid >> 4, cc = tid & 15;
#pragma unroll
        for (int rep = 0; rep < 8; ++rep) {
            const int l = rep * 16 + rr;
            us8 v = *(const us8*)&smem[l * TST + cc * 8];
            *(us8*)&Xb[(size_t)(l0 + l) * BS + (size_t)b * DS + s0 + cc * 8] = v;
        }
    }
}

// ---------------------------------------------------------------------------
__global__ __launch_bounds__(256) void k_carry(const float* __restrict__ finals,
                                               float* __restrict__ carries,
                                               const float* __restrict__ apow,
                                               const float* __restrict__ h0) {
    const int bs = blockIdx.x * 256 + threadIdx.x;
    const int s = bs & (DS - 1);
    const float aT = apow[CT * DS + s];
    float carry = h0[s];
    for (int c = 0; c < CH; ++c) {
        carries[(size_t)c * BS + bs] = carry;
        carry = aT * carry + finals[(size_t)c * BS + bs];
    }
}

// ---------------------------------------------------------------------------
// k_out: Y = C @ (X + a^{j+1} carry) + D @ u. Single-barrier dbuf pipelines.
// LDS layout (ushort offsets): A0=0, A1=5120 (stride 40); B0=10240, B1=14336.
// ---------------------------------------------------------------------------
__global__ __launch_bounds__(256) void k_out(const ushort* __restrict__ Cmb,
                                             const ushort* __restrict__ Dmb,
                                             const ushort* __restrict__ Xb,
                                             const ushort* __restrict__ utr,
                                             const float* __restrict__ carries,
                                             const float* __restrict__ apow,
                                             float* __restrict__ Y) {
    __shared__ ushort smem[18432];   // 36.9 KB
    const int tid = threadIdx.x;
    const int w = tid >> 6, lane = tid & 63;
    const int l0 = blockIdx.x * 128, o0 = blockIdx.y * 128, b = blockIdx.z;
    const int wm = w & 1, wn = w >> 1;
    const int mrow = lane & 15, quad = lane >> 4;
    const int sr = lane >> 2, sc = (lane & 3) * 8;
    const int off0 = (16 * w) * 32, off1 = (16 * w + 64) * 32;

    f32x4 acc[4][4];
#pragma unroll
    for (int mi = 0; mi < 4; ++mi)
#pragma unroll
        for (int ni = 0; ni < 4; ++ni) acc[mi][ni] = (f32x4)0.f;

    auto compute = [&](const int aoff, const int ast, const int boff) {
        bf16x8 af[4], bfr[4];
#pragma unroll
        for (int mi = 0; mi < 4; ++mi)
            af[mi] = *(const bf16x8*)&smem[aoff + (wm * 64 + mi * 16 + mrow) * ast + quad * 8];
#pragma unroll
        for (int ni = 0; ni < 4; ++ni)
            bfr[ni] = *(const bf16x8*)&smem[boff + (wn * 64 + ni * 16 + mrow) * 32 + quad * 8];
#pragma unroll
        for (int mi = 0; mi < 4; ++mi)
#pragma unroll
            for (int ni = 0; ni < 4; ++ni)
                acc[mi][ni] = __builtin_amdgcn_mfma_f32_16x16x32_bf16(af[mi], bfr[ni], acc[mi][ni], 0, 0, 0);
    };

    { // phase 1: C @ X_corrected, K = DS, 16 iters
        const int r0 = 16 * w + sr;
        const int l_0 = l0 + r0, l_1 = l_0 + 64;
        const int j0 = l_0 & 63, c0 = l_0 >> 6;
        const int j1 = l_1 & 63, c1 = l_1 >> 6;
        const float* ap0 = &apow[(size_t)(j0 + 1) * DS];
        const float* ap1 = &apow[(size_t)(j1 + 1) * DS];
        const float* cr0 = &carries[(size_t)c0 * BS + (size_t)b * DS];
        const float* cr1 = &carries[(size_t)c1 * BS + (size_t)b * DS];
        const ushort* x0 = Xb + (size_t)l_0 * BS + (size_t)b * DS;
        const ushort* x1 = Xb + (size_t)l_1 * BS + (size_t)b * DS;
        const ushort* bg0 = Cmb + (size_t)(o0 + r0) * DS + sc;
        const ushort* bg1 = bg0 + (size_t)64 * DS;

        auto stageA = [&](int it, int dstoff) {
            const int col = it * 32 + sc;
            {
                us8 x = *(const us8*)&x0[col];
                float4 pa = *(const float4*)&ap0[col], pb = *(const float4*)&ap0[col + 4];
                float4 ca = *(const float4*)&cr0[col], cb = *(const float4*)&cr0[col + 4];
                us8 o;
                o[0] = f2b(b2f(x[0]) + pa.x * ca.x); o[1] = f2b(b2f(x[1]) + pa.y * ca.y);
                o[2] = f2b(b2f(x[2]) + pa.z * ca.z); o[3] = f2b(b2f(x[3]) + pa.w * ca.w);
                o[4] = f2b(b2f(x[4]) + pb.x * cb.x); o[5] = f2b(b2f(x[5]) + pb.y * cb.y);
                o[6] = f2b(b2f(x[6]) + pb.z * cb.z); o[7] = f2b(b2f(x[7]) + pb.w * cb.w);
                *(us8*)&smem[dstoff + r0 * 40 + sc] = o;
            }
            {
                us8 x = *(const us8*)&x1[col];
                float4 pa = *(const float4*)&ap1[col], pb = *(const float4*)&ap1[col + 4];
                float4 ca = *(const float4*)&cr1[col], cb = *(const float4*)&cr1[col + 4];
                us8 o;
                o[0] = f2b(b2f(x[0]) + pa.x * ca.x); o[1] = f2b(b2f(x[1]) + pa.y * ca.y);
                o[2] = f2b(b2f(x[2]) + pa.z * ca.z); o[3] = f2b(b2f(x[3]) + pa.w * ca.w);
                o[4] = f2b(b2f(x[4]) + pb.x * cb.x); o[5] = f2b(b2f(x[5]) + pb.y * cb.y);
                o[6] = f2b(b2f(x[6]) + pb.z * cb.z); o[7] = f2b(b2f(x[7]) + pb.w * cb.w);
                *(us8*)&smem[dstoff + (r0 + 64) * 40 + sc] = o;
            }
        };

        // prologue into buffer 0
        stageA(0, 0);
        gload16(bg0, smem + 10240 + off0); gload16(bg1, smem + 10240 + off1);

        for (int it = 0; it < DS / 32; ++it) {
            __syncthreads();
            const int ca_ = (it & 1) * 5120, na_ = 5120 - ca_;
            const int cb_ = 10240 + (it & 1) * 4096, nb_ = 10240 + 4096 - (it & 1) * 4096;
            if (it + 1 < DS / 32) {
                const int kk = (it + 1) * 32;
                gload16(bg0 + kk, smem + nb_ + off0); gload16(bg1 + kk, smem + nb_ + off1);
                stageA(it + 1, na_);
            }
            compute(ca_, 40, cb_);
        }
    }
    { // phase 2: D @ u, K = DI, 8 iters (A dbuf at 0/5120 region, stride 32)
        const ushort* ag0 = utr + ((size_t)b * LL + l0 + 16 * w + sr) * DI + sc;
        const ushort* ag1 = ag0 + (size_t)64 * DI;
        const ushort* bg0 = Dmb + (size_t)(o0 + 16 * w + sr) * DI + sc;
        const ushort* bg1 = bg0 + (size_t)64 * DI;

        __syncthreads();   // all phase-1 reads done before reusing buffers
        gload16(ag0, smem + off0); gload16(ag1, smem + off1);
        gload16(bg0, smem + 10240 + off0); gload16(bg1, smem + 10240 + off1);

        for (int it = 0; it < DI / 32; ++it) {
            __syncthreads();
            const int ca_ = (it & 1) * 5120, na_ = 5120 - ca_;
            const int cb_ = 10240 + (it & 1) * 4096, nb_ = 10240 + 4096 - (it & 1) * 4096;
            if (it + 1 < DI / 32) {
                const int kk = (it + 1) * 32;
                gload16(ag0 + kk, smem + na_ + off0); gload16(ag1 + kk, smem + na_ + off1);
                gload16(bg0 + kk, smem + nb_ + off0); gload16(bg1 + kk, smem + nb_ + off1);
            }
            compute(ca_, 32, cb_);
        }
    }

#pragma unroll
    for (int mi = 0; mi < 4; ++mi) {
        const int l = l0 + wm * 64 + mi * 16 + quad * 4;
#pragma unroll
        for (int ni = 0; ni < 4; ++ni) {
            const int o = o0 + wn * 64 + ni * 16 + mrow;
            *(float4*)&Y[((size_t)b * DOUT + o) * LL + l] = *(float4*)&acc[mi][ni];
        }
    }
}

// ---------------------------------------------------------------------------
extern "C" void kernel_launch(void* const* d_in, const int* in_sizes, int n_in,
                              void* d_out, int out_size, void* d_ws, size_t ws_size,
                              hipStream_t stream) {
    const float* u  = (const float*)d_in[0];
    const float* Au = (const float*)d_in[1];
    const float* Bm = (const float*)d_in[2];
    const float* Cm = (const float*)d_in[3];
    const float* Dm = (const float*)d_in[4];
    const float* h0 = (const float*)d_in[5];
    float* Y = (float*)d_out;

    char* p = (char*)d_ws;
    ushort* utr    = (ushort*)p; p += (size_t)BZ * LL * DI * 2;
    ushort* Xb     = (ushort*)p; p += (size_t)LL * BS * 2;
    float* finals  = (float*)p;  p += (size_t)CH * BS * 4;
    float* carries = (float*)p;  p += (size_t)CH * BS * 4;
    float* apow    = (float*)p;  p += (size_t)(CT + 1) * DS * 4;
    ushort* Bmb    = (ushort*)p; p += (size_t)DS * DI * 2;
    ushort* Cmb    = (ushort*)p; p += (size_t)DOUT * DS * 2;
    ushort* Dmb    = (ushort*)p; p += (size_t)DOUT * DI * 2;

    k_prep<<<dim3(320), 256, 0, stream>>>(Au, apow, Bm, Cm, Dm, Bmb, Cmb, Dmb);
    k_u2t<<<dim3(LL / 64, DI / 64, BZ), 256, 0, stream>>>(u, utr);
    k_bu<<<dim3(LL / 128, DS / 128, BZ), 256, 0, stream>>>(Bmb, utr, Xb, finals, apow);
    k_carry<<<dim3(BS / 256), 256, 0, stream>>>(finals, carries, apow, h0);
    k_out<<<dim3(LL / 128, DOUT / 128, BZ), 256, 0, stream>>>(Cmb, Dmb, Xb, utr, carries, apow, Y);
}

// Round 7
// 145.422 us; speedup vs baseline: 2.8808x; 1.0145x over previous
//
#include <hip/hip_runtime.h>
#include <math.h>

// SimpleSSM: u(B,DI,L) f32, A(S), B_mat(S,DI), C_mat(DO,S), D_mat(DO,DI), h0(S)
#define BZ 8
#define DI 256
#define DS 512
#define DOUT 256
#define LL 4096
#define BS (BZ * DS)   // 4096
#define CH 64
#define CT 64
#define TST 136        // k_bu scan-tile LDS stride in ushorts

typedef __bf16 bf16x8 __attribute__((ext_vector_type(8)));
typedef float f32x4 __attribute__((ext_vector_type(4)));
typedef unsigned short us8 __attribute__((ext_vector_type(8)));

__device__ __forceinline__ ushort f2b(float f) {
    union { float f; unsigned u; } v; v.f = f;
    unsigned r = v.u + 0x7FFFu + ((v.u >> 16) & 1u);
    return (ushort)(r >> 16);
}
__device__ __forceinline__ float b2f(ushort h) {
    union { unsigned u; float f; } v; v.u = ((unsigned)h) << 16;
    return v.f;
}

__device__ __forceinline__ void gload16(const ushort* g, ushort* l) {
    __builtin_amdgcn_global_load_lds(
        (const __attribute__((address_space(1))) unsigned int*)g,
        (__attribute__((address_space(3))) unsigned int*)l,
        16, 0, 0);
}

// ---------------------------------------------------------------------------
__global__ __launch_bounds__(256) void k_prep(const float* __restrict__ Au,
                                              float* __restrict__ apow,
                                              const float* __restrict__ Bm,
                                              const float* __restrict__ Cm,
                                              const float* __restrict__ Dm,
                                              ushort* __restrict__ Bmb,
                                              ushort* __restrict__ Cmb,
                                              ushort* __restrict__ Dmb,
                                              int* __restrict__ dflag) {
    const int t = blockIdx.x * 256 + threadIdx.x;
    const int n1 = DS * DI / 4, n2 = DOUT * DS / 4, n3 = DOUT * DI / 4;
    if (t < n1) {
        float4 v = ((const float4*)Bm)[t];
        ushort4 o; o.x = f2b(v.x); o.y = f2b(v.y); o.z = f2b(v.z); o.w = f2b(v.w);
        ((ushort4*)Bmb)[t] = o;
    } else if (t < n1 + n2) {
        float4 v = ((const float4*)Cm)[t - n1];
        ushort4 o; o.x = f2b(v.x); o.y = f2b(v.y); o.z = f2b(v.z); o.w = f2b(v.w);
        ((ushort4*)Cmb)[t - n1] = o;
    } else if (t < n1 + n2 + n3) {
        float4 v = ((const float4*)Dm)[t - n1 - n2];
        ushort4 o; o.x = f2b(v.x); o.y = f2b(v.y); o.z = f2b(v.z); o.w = f2b(v.w);
        ((ushort4*)Dmb)[t - n1 - n2] = o;
        // D==0 detection: any nonzero element sets the flag (exact test)
        if (v.x != 0.f || v.y != 0.f || v.z != 0.f || v.w != 0.f)
            atomicOr(dflag, 1);
    }
    if (t < DS) {
        float x = Au[t];
        float sp = (x > 15.f) ? x : log1pf(expf(x));
        float ad = -sp;
        float p = 1.f;
        apow[t] = 1.f;
        for (int j = 1; j <= CT; ++j) { p *= ad; apow[j * DS + t] = p; }
    }
}

// ---------------------------------------------------------------------------
__global__ __launch_bounds__(256) void k_u2t(const float* __restrict__ u,
                                             ushort* __restrict__ utr) {
    __shared__ float T[64][65];
    const int tid = threadIdx.x;
    const int l0 = blockIdx.x * 64, i0 = blockIdx.y * 64, b = blockIdx.z;
    const int r = tid >> 4, c4 = tid & 15;
#pragma unroll
    for (int rr = r; rr < 64; rr += 16) {
        float4 v = *(const float4*)&u[((size_t)b * DI + i0 + rr) * LL + l0 + c4 * 4];
        T[rr][c4 * 4 + 0] = v.x; T[rr][c4 * 4 + 1] = v.y;
        T[rr][c4 * 4 + 2] = v.z; T[rr][c4 * 4 + 3] = v.w;
    }
    __syncthreads();
#pragma unroll
    for (int ll = r; ll < 64; ll += 16) {
        ushort4 o;
        o.x = f2b(T[c4 * 4 + 0][ll]); o.y = f2b(T[c4 * 4 + 1][ll]);
        o.z = f2b(T[c4 * 4 + 2][ll]); o.w = f2b(T[c4 * 4 + 3][ll]);
        *(ushort4*)&utr[((size_t)b * LL + l0 + ll) * DI + i0 + c4 * 4] = o;
    }
}

// ---------------------------------------------------------------------------
// k_bu: Xb = local-scanned(B @ u) + finals. Single-barrier dbuf K-loop.
// ---------------------------------------------------------------------------
__global__ __launch_bounds__(256) void k_bu(const ushort* __restrict__ Bmb,
                                            const ushort* __restrict__ utr,
                                            ushort* __restrict__ Xb,
                                            float* __restrict__ finals,
                                            const float* __restrict__ apow) {
    __shared__ ushort smem[128 * TST];   // 34.8 KB; GEMM dbuf = first 32 KB
    const int tid = threadIdx.x;
    const int w = tid >> 6, lane = tid & 63;
    const int l0 = blockIdx.x * 128, s0 = blockIdx.y * 128, b = blockIdx.z;
    const int wm = w & 1, wn = w >> 1;
    const int mrow = lane & 15, quad = lane >> 4;
    const int sr = lane >> 2, sc = (lane & 3) * 8;
    const int off0 = (16 * w) * 32, off1 = (16 * w + 64) * 32;

    f32x4 acc[4][4];
#pragma unroll
    for (int mi = 0; mi < 4; ++mi)
#pragma unroll
        for (int ni = 0; ni < 4; ++ni) acc[mi][ni] = (f32x4)0.f;

    const ushort* ag0 = Bmb + (size_t)(s0 + 16 * w + sr) * DI + sc;
    const ushort* ag1 = ag0 + (size_t)64 * DI;
    const ushort* bg0 = utr + ((size_t)b * LL + l0 + 16 * w + sr) * DI + sc;
    const ushort* bg1 = bg0 + (size_t)64 * DI;

    gload16(ag0, smem + off0); gload16(ag1, smem + off1);
    gload16(bg0, smem + 8192 + off0); gload16(bg1, smem + 8192 + off1);

    for (int it = 0; it < DI / 32; ++it) {
        __syncthreads();
        const int cb = (it & 1) * 4096, nb = 4096 - cb;
        if (it + 1 < DI / 32) {
            const int kk = (it + 1) * 32;
            gload16(ag0 + kk, smem + nb + off0); gload16(ag1 + kk, smem + nb + off1);
            gload16(bg0 + kk, smem + 8192 + nb + off0); gload16(bg1 + kk, smem + 8192 + nb + off1);
        }
        bf16x8 af[4], bfr[4];
#pragma unroll
        for (int mi = 0; mi < 4; ++mi)
            af[mi] = *(const bf16x8*)&smem[cb + (wm * 64 + mi * 16 + mrow) * 32 + quad * 8];
#pragma unroll
        for (int ni = 0; ni < 4; ++ni)
            bfr[ni] = *(const bf16x8*)&smem[8192 + cb + (wn * 64 + ni * 16 + mrow) * 32 + quad * 8];
#pragma unroll
        for (int mi = 0; mi < 4; ++mi)
#pragma unroll
            for (int ni = 0; ni < 4; ++ni)
                acc[mi][ni] = __builtin_amdgcn_mfma_f32_16x16x32_bf16(af[mi], bfr[ni], acc[mi][ni], 0, 0, 0);
    }
    __syncthreads();

#pragma unroll
    for (int mi = 0; mi < 4; ++mi) {
        const int sloc = wm * 64 + mi * 16 + quad * 4;
#pragma unroll
        for (int ni = 0; ni < 4; ++ni) {
            const int lloc = wn * 64 + ni * 16 + mrow;
            f32x4 v = acc[mi][ni];
            ushort4 o; o.x = f2b(v[0]); o.y = f2b(v[1]); o.z = f2b(v[2]); o.w = f2b(v[3]);
            *(ushort4*)&smem[lloc * TST + sloc] = o;
        }
    }
    __syncthreads();
    {
        const int cloc = tid >> 7, sl = tid & 127;
        const float a = apow[DS + s0 + sl];
        float acc2 = 0.f;
        ushort* p = &smem[(cloc * 64) * TST + sl];
#pragma unroll 8
        for (int j = 0; j < CT; ++j) {
            acc2 = a * acc2 + b2f(*p);
            *p = f2b(acc2);
            p += TST;
        }
        finals[(size_t)(l0 / 64 + cloc) * BS + (size_t)b * DS + s0 + sl] = acc2;
    }
    __syncthreads();
    {
        const int rr = tid >> 4, cc = tid & 15;
#pragma unroll
        for (int rep = 0; rep < 8; ++rep) {
            const int l = rep * 16 + rr;
            us8 v = *(const us8*)&smem[l * TST + cc * 8];
            *(us8*)&Xb[(size_t)(l0 + l) * BS + (size_t)b * DS + s0 + cc * 8] = v;
        }
    }
}

// ---------------------------------------------------------------------------
__global__ __launch_bounds__(256) void k_carry(const float* __restrict__ finals,
                                               float* __restrict__ carries,
                                               const float* __restrict__ apow,
                                               const float* __restrict__ h0) {
    const int bs = blockIdx.x * 256 + threadIdx.x;
    const int s = bs & (DS - 1);
    const float aT = apow[CT * DS + s];
    float carry = h0[s];
#pragma unroll 8
    for (int c = 0; c < CH; ++c) {
        carries[(size_t)c * BS + bs] = carry;
        carry = aT * carry + finals[(size_t)c * BS + bs];
    }
}

// ---------------------------------------------------------------------------
// k_out: Y = C @ (X + a^{j+1} carry) [+ D @ u if D != 0]. dbuf pipelines.
// ---------------------------------------------------------------------------
__global__ __launch_bounds__(256) void k_out(const ushort* __restrict__ Cmb,
                                             const ushort* __restrict__ Dmb,
                                             const ushort* __restrict__ Xb,
                                             const ushort* __restrict__ utr,
                                             const float* __restrict__ carries,
                                             const float* __restrict__ apow,
                                             const int* __restrict__ dflag,
                                             float* __restrict__ Y) {
    __shared__ ushort smem[18432];   // 36.9 KB
    const int tid = threadIdx.x;
    const int w = tid >> 6, lane = tid & 63;
    const int l0 = blockIdx.x * 128, o0 = blockIdx.y * 128, b = blockIdx.z;
    const int wm = w & 1, wn = w >> 1;
    const int mrow = lane & 15, quad = lane >> 4;
    const int sr = lane >> 2, sc = (lane & 3) * 8;
    const int off0 = (16 * w) * 32, off1 = (16 * w + 64) * 32;
    const int dnz = *dflag;          // wave-uniform: run D-phase only if D != 0

    f32x4 acc[4][4];
#pragma unroll
    for (int mi = 0; mi < 4; ++mi)
#pragma unroll
        for (int ni = 0; ni < 4; ++ni) acc[mi][ni] = (f32x4)0.f;

    auto compute = [&](const int aoff, const int ast, const int boff) {
        bf16x8 af[4], bfr[4];
#pragma unroll
        for (int mi = 0; mi < 4; ++mi)
            af[mi] = *(const bf16x8*)&smem[aoff + (wm * 64 + mi * 16 + mrow) * ast + quad * 8];
#pragma unroll
        for (int ni = 0; ni < 4; ++ni)
            bfr[ni] = *(const bf16x8*)&smem[boff + (wn * 64 + ni * 16 + mrow) * 32 + quad * 8];
#pragma unroll
        for (int mi = 0; mi < 4; ++mi)
#pragma unroll
            for (int ni = 0; ni < 4; ++ni)
                acc[mi][ni] = __builtin_amdgcn_mfma_f32_16x16x32_bf16(af[mi], bfr[ni], acc[mi][ni], 0, 0, 0);
    };

    { // phase 1: C @ X_corrected, K = DS, 16 iters
        const int r0 = 16 * w + sr;
        const int l_0 = l0 + r0, l_1 = l_0 + 64;
        const int j0 = l_0 & 63, c0 = l_0 >> 6;
        const int j1 = l_1 & 63, c1 = l_1 >> 6;
        const float* ap0 = &apow[(size_t)(j0 + 1) * DS];
        const float* ap1 = &apow[(size_t)(j1 + 1) * DS];
        const float* cr0 = &carries[(size_t)c0 * BS + (size_t)b * DS];
        const float* cr1 = &carries[(size_t)c1 * BS + (size_t)b * DS];
        const ushort* x0 = Xb + (size_t)l_0 * BS + (size_t)b * DS;
        const ushort* x1 = Xb + (size_t)l_1 * BS + (size_t)b * DS;
        const ushort* bg0 = Cmb + (size_t)(o0 + r0) * DS + sc;
        const ushort* bg1 = bg0 + (size_t)64 * DS;

        auto stageA = [&](int it, int dstoff) {
            const int col = it * 32 + sc;
            {
                us8 x = *(const us8*)&x0[col];
                float4 pa = *(const float4*)&ap0[col], pb = *(const float4*)&ap0[col + 4];
                float4 ca = *(const float4*)&cr0[col], cb = *(const float4*)&cr0[col + 4];
                us8 o;
                o[0] = f2b(b2f(x[0]) + pa.x * ca.x); o[1] = f2b(b2f(x[1]) + pa.y * ca.y);
                o[2] = f2b(b2f(x[2]) + pa.z * ca.z); o[3] = f2b(b2f(x[3]) + pa.w * ca.w);
                o[4] = f2b(b2f(x[4]) + pb.x * cb.x); o[5] = f2b(b2f(x[5]) + pb.y * cb.y);
                o[6] = f2b(b2f(x[6]) + pb.z * cb.z); o[7] = f2b(b2f(x[7]) + pb.w * cb.w);
                *(us8*)&smem[dstoff + r0 * 40 + sc] = o;
            }
            {
                us8 x = *(const us8*)&x1[col];
                float4 pa = *(const float4*)&ap1[col], pb = *(const float4*)&ap1[col + 4];
                float4 ca = *(const float4*)&cr1[col], cb = *(const float4*)&cr1[col + 4];
                us8 o;
                o[0] = f2b(b2f(x[0]) + pa.x * ca.x); o[1] = f2b(b2f(x[1]) + pa.y * ca.y);
                o[2] = f2b(b2f(x[2]) + pa.z * ca.z); o[3] = f2b(b2f(x[3]) + pa.w * ca.w);
                o[4] = f2b(b2f(x[4]) + pb.x * cb.x); o[5] = f2b(b2f(x[5]) + pb.y * cb.y);
                o[6] = f2b(b2f(x[6]) + pb.z * cb.z); o[7] = f2b(b2f(x[7]) + pb.w * cb.w);
                *(us8*)&smem[dstoff + (r0 + 64) * 40 + sc] = o;
            }
        };

        stageA(0, 0);
        gload16(bg0, smem + 10240 + off0); gload16(bg1, smem + 10240 + off1);

        for (int it = 0; it < DS / 32; ++it) {
            __syncthreads();
            const int ca_ = (it & 1) * 5120, na_ = 5120 - ca_;
            const int cb_ = 10240 + (it & 1) * 4096, nb_ = 10240 + 4096 - (it & 1) * 4096;
            if (it + 1 < DS / 32) {
                const int kk = (it + 1) * 32;
                gload16(bg0 + kk, smem + nb_ + off0); gload16(bg1 + kk, smem + nb_ + off1);
                stageA(it + 1, na_);
            }
            compute(ca_, 40, cb_);
        }
    }
    if (dnz) { // phase 2: D @ u, K = DI, 8 iters — only when D has nonzeros
        const ushort* ag0 = utr + ((size_t)b * LL + l0 + 16 * w + sr) * DI + sc;
        const ushort* ag1 = ag0 + (size_t)64 * DI;
        const ushort* bg0 = Dmb + (size_t)(o0 + 16 * w + sr) * DI + sc;
        const ushort* bg1 = bg0 + (size_t)64 * DI;

        __syncthreads();
        gload16(ag0, smem + off0); gload16(ag1, smem + off1);
        gload16(bg0, smem + 10240 + off0); gload16(bg1, smem + 10240 + off1);

        for (int it = 0; it < DI / 32; ++it) {
            __syncthreads();
            const int ca_ = (it & 1) * 5120, na_ = 5120 - ca_;
            const int cb_ = 10240 + (it & 1) * 4096, nb_ = 10240 + 4096 - (it & 1) * 4096;
            if (it + 1 < DI / 32) {
                const int kk = (it + 1) * 32;
                gload16(ag0 + kk, smem + na_ + off0); gload16(ag1 + kk, smem + na_ + off1);
                gload16(bg0 + kk, smem + nb_ + off0); gload16(bg1 + kk, smem + nb_ + off1);
            }
            compute(ca_, 32, cb_);
        }
    }

#pragma unroll
    for (int mi = 0; mi < 4; ++mi) {
        const int l = l0 + wm * 64 + mi * 16 + quad * 4;
#pragma unroll
        for (int ni = 0; ni < 4; ++ni) {
            const int o = o0 + wn * 64 + ni * 16 + mrow;
            *(float4*)&Y[((size_t)b * DOUT + o) * LL + l] = *(float4*)&acc[mi][ni];
        }
    }
}

// ---------------------------------------------------------------------------
extern "C" void kernel_launch(void* const* d_in, const int* in_sizes, int n_in,
                              void* d_out, int out_size, void* d_ws, size_t ws_size,
                              hipStream_t stream) {
    const float* u  = (const float*)d_in[0];
    const float* Au = (const float*)d_in[1];
    const float* Bm = (const float*)d_in[2];
    const float* Cm = (const float*)d_in[3];
    const float* Dm = (const float*)d_in[4];
    const float* h0 = (const float*)d_in[5];
    float* Y = (float*)d_out;

    char* p = (char*)d_ws;
    ushort* utr    = (ushort*)p; p += (size_t)BZ * LL * DI * 2;
    ushort* Xb     = (ushort*)p; p += (size_t)LL * BS * 2;
    float* finals  = (float*)p;  p += (size_t)CH * BS * 4;
    float* carries = (float*)p;  p += (size_t)CH * BS * 4;
    float* apow    = (float*)p;  p += (size_t)(CT + 1) * DS * 4;
    ushort* Bmb    = (ushort*)p; p += (size_t)DS * DI * 2;
    ushort* Cmb    = (ushort*)p; p += (size_t)DOUT * DS * 2;
    ushort* Dmb    = (ushort*)p; p += (size_t)DOUT * DI * 2;
    int* dflag     = (int*)p;    p += 16;

    hipMemsetAsync(dflag, 0, 4, stream);
    k_prep<<<dim3(320), 256, 0, stream>>>(Au, apow, Bm, Cm, Dm, Bmb, Cmb, Dmb, dflag);
    k_u2t<<<dim3(LL / 64, DI / 64, BZ), 256, 0, stream>>>(u, utr);
    k_bu<<<dim3(LL / 128, DS / 128, BZ), 256, 0, stream>>>(Bmb, utr, Xb, finals, apow);
    k_carry<<<dim3(BS / 256), 256, 0, stream>>>(finals, carries, apow, h0);
    k_out<<<dim3(LL / 128, DOUT / 128, BZ), 256, 0, stream>>>(Cmb, Dmb, Xb, utr, carries, apow, dflag, Y);
}